// Round 2
// baseline (465.915 us; speedup 1.0000x reference)
//
#include <hip/hip_runtime.h>
#include <cstdint>
#include <cstddef>

typedef unsigned short u16;
typedef __attribute__((ext_vector_type(8))) short short8;
typedef __attribute__((ext_vector_type(4))) float floatx4;

#define DEVI __device__ __forceinline__

constexpr int Bb  = 2;
constexpr int Ss  = 2048;
constexpr int Hh  = 2048;
constexpr int NH  = 16;
constexpr int NKV = 4;
constexpr int HD  = 128;
constexpr int MROWS = Bb * Ss;  // 4096

DEVI u16 f2bf(float f) {
  union { float f; unsigned u; } v; v.f = f;
  unsigned r = v.u + 0x7fffu + ((v.u >> 16) & 1u);
  return (u16)(r >> 16);
}

// async global->LDS, 16B per lane. LDS dest must be wave-uniform base + lane*16.
DEVI void llds16(const u16* g, u16* l) {
  __builtin_amdgcn_global_load_lds(
      (const __attribute__((address_space(1))) void*)g,
      (__attribute__((address_space(3))) void*)l, 16, 0, 0);
}

// ---------- fp32 -> bf16 convert (vectorized) ----------
__global__ void k_f2b(const float4* __restrict__ in, ushort4* __restrict__ out, int n4) {
  int i = blockIdx.x * blockDim.x + threadIdx.x;
  if (i < n4) {
    float4 v = in[i];
    ushort4 o;
    o.x = f2bf(v.x); o.y = f2bf(v.y); o.z = f2bf(v.z); o.w = f2bf(v.w);
    out[i] = o;
  }
}

// ---------- transpose + convert: in (K,N) fp32 row-major -> out (N,K) bf16 ----------
__global__ void k_tw(const float* __restrict__ in, u16* __restrict__ out, int K, int N) {
  __shared__ float tile[32][33];
  int n0 = blockIdx.x * 32, k0 = blockIdx.y * 32;
  int tx = threadIdx.x & 31, ty = threadIdx.x >> 5;  // 256 threads
  for (int i = ty; i < 32; i += 8)
    tile[i][tx] = in[(size_t)(k0 + i) * N + n0 + tx];
  __syncthreads();
  for (int i = ty; i < 32; i += 8)
    out[(size_t)(n0 + i) * K + k0 + tx] = f2bf(tile[tx][i]);
}

// ---------- m97-style GEMM: C(M,N) fp32 = A(M,K) bf16 @ Bt(N,K)^T bf16 ----------
// 128x128 tile, BK=32, 256 threads / 4 waves, 16x16x32 bf16 MFMA.
__global__ __launch_bounds__(256) void k_gemm(const u16* __restrict__ A, const u16* __restrict__ Bt,
                                              float* __restrict__ C, int M, int N, int K) {
  __shared__ u16 As[128 * 32];
  __shared__ u16 Bs[128 * 32];
  const int t = threadIdx.x;
  const int lane = t & 63, w = t >> 6;
  const int q4 = lane >> 4, l16 = lane & 15;
  const int m0 = blockIdx.y * 128, n0 = blockIdx.x * 128;
  const int wm = (w >> 1) * 64, wn = (w & 1) * 64;

  floatx4 acc[4][4];
#pragma unroll
  for (int i = 0; i < 4; ++i)
#pragma unroll
    for (int j = 0; j < 4; ++j) acc[i][j] = floatx4{0.f, 0.f, 0.f, 0.f};

  const u16* Ab = A + (size_t)m0 * K;
  const u16* Bp = Bt + (size_t)n0 * K;

  for (int k0 = 0; k0 < K; k0 += 32) {
#pragma unroll
    for (int it = 0; it < 2; ++it) {
      int c = it * 256 + t;         // 512 chunks of 16B per 128x32 tile
      int row = c >> 2, c8 = (c & 3) * 8;
      llds16(Ab + (size_t)row * K + k0 + c8, &As[c * 8]);
      llds16(Bp + (size_t)row * K + k0 + c8, &Bs[c * 8]);
    }
    __syncthreads();
    short8 af[4], bfr[4];
#pragma unroll
    for (int tm = 0; tm < 4; ++tm)
      af[tm] = *(const short8*)&As[(wm + tm * 16 + l16) * 32 + q4 * 8];
#pragma unroll
    for (int tn = 0; tn < 4; ++tn)
      bfr[tn] = *(const short8*)&Bs[(wn + tn * 16 + l16) * 32 + q4 * 8];
#pragma unroll
    for (int tm = 0; tm < 4; ++tm)
#pragma unroll
      for (int tn = 0; tn < 4; ++tn)
        acc[tm][tn] = __builtin_amdgcn_mfma_f32_16x16x32_bf16(af[tm], bfr[tn], acc[tm][tn], 0, 0, 0);
    __syncthreads();
  }
  // C/D layout: col = lane&15, row = quad*4 + reg (m89-verified)
#pragma unroll
  for (int tm = 0; tm < 4; ++tm) {
    int rb = m0 + wm + tm * 16 + q4 * 4;
#pragma unroll
    for (int tn = 0; tn < 4; ++tn) {
      int col = n0 + wn + tn * 16 + l16;
#pragma unroll
      for (int r = 0; r < 4; ++r)
        C[(size_t)(rb + r) * N + col] = acc[tm][tn][r];
    }
  }
}

// ---------- RoPE: in fp32 (B,S,*,instride cols) -> out bf16 (B,S,nheads,HD), scale folded ----------
__global__ void k_rope(const float* __restrict__ in, u16* __restrict__ out,
                       int nheads, int instride, float scale) {
  int idx = blockIdx.x * blockDim.x + threadIdx.x;
  int j = idx & 63;
  int tmp = idx >> 6;
  int h = tmp % nheads; tmp /= nheads;   // tmp = b*S + s
  int s = tmp % Ss;
  const float* ip = in + (size_t)tmp * instride + h * HD;
  u16* op = out + ((size_t)tmp * nheads + h) * HD;
  // inv = 10000^(-2j/HD) ; angle = s * inv
  float inv = exp2f(-(float)(2 * j) * (13.287712379549449f / (float)HD));
  float ang = (float)s * inv;
  float c = cosf(ang), sn = sinf(ang);
  float x1 = ip[j], x2 = ip[j + 64];
  op[j]      = f2bf((x1 * c - x2 * sn) * scale);
  op[j + 64] = f2bf((x2 * c + x1 * sn) * scale);
}

// ---------- V transpose: fp32 (B,S,[coloff+g*HD+d] of instride) -> bf16 Vt (B,NKV,HD,S) ----------
__global__ void k_vt(const float* __restrict__ V, u16* __restrict__ Vt, int instride, int coloff) {
  __shared__ float tile[32][33];
  int bg = blockIdx.z;                 // b*NKV + g
  int s0 = blockIdx.x * 32;
  int d0 = blockIdx.y * 32;
  int tx = threadIdx.x & 31, ty = threadIdx.x >> 5;
  int b = bg / NKV, g = bg % NKV;
  const float* vin = V + (size_t)(b * Ss) * instride + coloff + g * HD;
  for (int i = ty; i < 32; i += 8)
    tile[i][tx] = vin[(size_t)(s0 + i) * instride + d0 + tx];
  __syncthreads();
  u16* vout = Vt + (size_t)bg * HD * Ss;
  for (int i = ty; i < 32; i += 8)
    vout[(size_t)(d0 + i) * Ss + s0 + tx] = f2bf(tile[tx][i]);
}

// ---------- flash attention: Q(B,S,NH,HD) bf16 (pre-scaled), K(B,S,NKV,HD) bf16, Vt(B,NKV,HD,S) bf16 ----------
// 64-row Q tile x 64-key tile, 4 waves (16 q-rows each). Block handles qb = x and 31-x (balanced triangle).
__global__ __launch_bounds__(256) void k_flash(const u16* __restrict__ Q, const u16* __restrict__ Kk,
                                               const u16* __restrict__ Vt, u16* __restrict__ O) {
  __shared__ u16 Kts[64 * 128];   // [sk][d]
  __shared__ u16 Vts[128 * 64];   // [d][sk]
  __shared__ u16 Ps[64 * 64];     // [q][sk], per-wave-private rows
  const int t = threadIdx.x, lane = t & 63, w = t >> 6;
  const int q4 = lane >> 4, l16 = lane & 15;
  const int h = blockIdx.y, b = blockIdx.z, g = h >> 2;  // NREP=4
  const u16* Qh = Q + ((size_t)b * Ss * NH + h) * HD;
  const u16* Kh = Kk + ((size_t)b * Ss * NKV + g) * HD;
  const u16* Vh = Vt + (size_t)(b * NKV + g) * HD * Ss;
  u16* Oh = O + ((size_t)b * Ss * NH + h) * HD;

  for (int hf = 0; hf < 2; ++hf) {
    const int qb = hf ? (31 - (int)blockIdx.x) : (int)blockIdx.x;
    const int q0 = qb * 64;
    // Q fragments (loop-invariant): A-layout A[m=lane&15][k=quad*8+j]
    const int qrow = q0 + w * 16 + l16;
    short8 qf[4];
#pragma unroll
    for (int kt = 0; kt < 4; ++kt)
      qf[kt] = *(const short8*)&Qh[(size_t)qrow * (NH * HD) + kt * 32 + q4 * 8];

    floatx4 oacc[8];
#pragma unroll
    for (int i = 0; i < 8; ++i) oacc[i] = floatx4{0.f, 0.f, 0.f, 0.f};
    float m_i[4] = {-1e30f, -1e30f, -1e30f, -1e30f};
    float l_i[4] = {0.f, 0.f, 0.f, 0.f};

    for (int kb = 0; kb <= qb; ++kb) {
      const int k0 = kb * 64;
#pragma unroll
      for (int it = 0; it < 4; ++it) {
        int c = it * 256 + t;   // 1024 chunks each
        llds16(Kh + (size_t)(k0 + (c >> 4)) * (NKV * HD) + (c & 15) * 8, &Kts[c * 8]);
        llds16(Vh + (size_t)(c >> 3) * Ss + k0 + (c & 7) * 8, &Vts[c * 8]);
      }
      __syncthreads();

      // S = Q K^T : 16 rows x 64 keys per wave
      floatx4 sc[4];
#pragma unroll
      for (int tn = 0; tn < 4; ++tn) sc[tn] = floatx4{0.f, 0.f, 0.f, 0.f};
#pragma unroll
      for (int kt = 0; kt < 4; ++kt)
#pragma unroll
        for (int tn = 0; tn < 4; ++tn) {
          short8 bfr = *(const short8*)&Kts[(tn * 16 + l16) * 128 + kt * 32 + q4 * 8];
          sc[tn] = __builtin_amdgcn_mfma_f32_16x16x32_bf16(qf[kt], bfr, sc[tn], 0, 0, 0);
        }

      if (kb == qb) {  // diagonal block: mask col > row (row includes this wave's 16-row band offset!)
#pragma unroll
        for (int tn = 0; tn < 4; ++tn) {
          int col = tn * 16 + l16;
#pragma unroll
          for (int r = 0; r < 4; ++r)
            if (col > w * 16 + q4 * 4 + r) sc[tn][r] = -1e30f;
        }
      }

      // online softmax; row r lives in quad q4, cols spread over 16 lanes
#pragma unroll
      for (int r = 0; r < 4; ++r) {
        float v = fmaxf(fmaxf(sc[0][r], sc[1][r]), fmaxf(sc[2][r], sc[3][r]));
#pragma unroll
        for (int off = 1; off < 16; off <<= 1) v = fmaxf(v, __shfl_xor(v, off));
        float mnew = fmaxf(m_i[r], v);
        float alpha = __expf(m_i[r] - mnew);
        m_i[r] = mnew;
        float rs = 0.f;
#pragma unroll
        for (int tn = 0; tn < 4; ++tn) {
          float p = __expf(sc[tn][r] - mnew);
          sc[tn][r] = p;
          rs += p;
        }
#pragma unroll
        for (int off = 1; off < 16; off <<= 1) rs += __shfl_xor(rs, off);
        l_i[r] = l_i[r] * alpha + rs;
#pragma unroll
        for (int td = 0; td < 8; ++td) oacc[td][r] *= alpha;
      }

      // P: C-layout -> LDS row-major -> A-layout reads (intra-wave rows only, no barrier needed)
#pragma unroll
      for (int tn = 0; tn < 4; ++tn)
#pragma unroll
        for (int r = 0; r < 4; ++r)
          Ps[(w * 16 + q4 * 4 + r) * 64 + tn * 16 + l16] = f2bf(sc[tn][r]);

      // O += P V
#pragma unroll
      for (int kt2 = 0; kt2 < 2; ++kt2) {
        short8 pa = *(const short8*)&Ps[(w * 16 + l16) * 64 + kt2 * 32 + q4 * 8];
#pragma unroll
        for (int td = 0; td < 8; ++td) {
          short8 vb = *(const short8*)&Vts[(td * 16 + l16) * 64 + kt2 * 32 + q4 * 8];
          oacc[td] = __builtin_amdgcn_mfma_f32_16x16x32_bf16(pa, vb, oacc[td], 0, 0, 0);
        }
      }
      __syncthreads();  // before next iter's staging overwrites Kts/Vts
    }

    // epilogue: O row = q0 + w*16 + quad*4 + r, col = td*16 + lane&15
#pragma unroll
    for (int td = 0; td < 8; ++td)
#pragma unroll
      for (int r = 0; r < 4; ++r) {
        float val = oacc[td][r] / l_i[r];
        Oh[(size_t)(q0 + w * 16 + q4 * 4 + r) * (NH * HD) + td * 16 + l16] = f2bf(val);
      }
  }
}

extern "C" void kernel_launch(void* const* d_in, const int* in_sizes, int n_in,
                              void* d_out, int out_size, void* d_ws, size_t ws_size,
                              hipStream_t stream) {
  (void)in_sizes; (void)n_in; (void)out_size; (void)ws_size;
  const float* x  = (const float*)d_in[0];
  const float* wq = (const float*)d_in[1];
  const float* wk = (const float*)d_in[2];
  const float* wv = (const float*)d_in[3];
  const float* wo = (const float*)d_in[4];
  float* out = (float*)d_out;

  char* ws = (char*)d_ws;
  size_t off = 0;
  auto alloc = [&](size_t bytes) {
    char* p = ws + off;
    off += (bytes + 255) & ~(size_t)255;
    return (void*)p;
  };
  u16*   xb   = (u16*)  alloc((size_t)MROWS * Hh * 2);        // also reused as O (bf16) later
  u16*   wqT  = (u16*)  alloc((size_t)2048 * 2048 * 2);
  u16*   wkvT = (u16*)  alloc((size_t)1024 * 2048 * 2);       // [wkT (512,2048) | wvT (512,2048)]
  u16*   woT  = (u16*)  alloc((size_t)2048 * 2048 * 2);
  float* qf   = (float*)alloc((size_t)MROWS * 2048 * 4);
  float* kvf  = (float*)alloc((size_t)MROWS * 1024 * 4);      // cols 0..511 = K, 512..1023 = V
  u16*   qb16 = (u16*)  alloc((size_t)MROWS * 2048 * 2);
  u16*   kb16 = (u16*)  alloc((size_t)MROWS * 512 * 2);
  u16*   vt16 = (u16*)  alloc((size_t)MROWS * 512 * 2);
  u16*   o16  = xb;  // xb dead after QKV projections

  // 1. x -> bf16
  k_f2b<<<dim3((MROWS * Hh / 4 + 255) / 256), dim3(256), 0, stream>>>(
      (const float4*)x, (ushort4*)xb, MROWS * Hh / 4);
  // 2. weights -> transposed bf16
  k_tw<<<dim3(64, 64), dim3(256), 0, stream>>>(wq, wqT, 2048, 2048);
  k_tw<<<dim3(16, 64), dim3(256), 0, stream>>>(wk, wkvT, 2048, 512);
  k_tw<<<dim3(16, 64), dim3(256), 0, stream>>>(wv, wkvT + (size_t)512 * 2048, 2048, 512);
  k_tw<<<dim3(64, 64), dim3(256), 0, stream>>>(wo, woT, 2048, 2048);
  // 3. projections (K,V fused -> N=1024, 256 blocks)
  k_gemm<<<dim3(16, 32), dim3(256), 0, stream>>>(xb, wqT, qf, MROWS, 2048, 2048);
  k_gemm<<<dim3(8, 32), dim3(256), 0, stream>>>(xb, wkvT, kvf, MROWS, 1024, 2048);
  // 4. RoPE (fold 1/sqrt(HD) into Q)
  k_rope<<<dim3(Bb * Ss * NH * 64 / 256), dim3(256), 0, stream>>>(qf, qb16, NH, 2048, 0.08838834764831845f);
  k_rope<<<dim3(Bb * Ss * NKV * 64 / 256), dim3(256), 0, stream>>>(kvf, kb16, NKV, 1024, 1.0f);
  // 5. V -> (B,NKV,HD,S) bf16
  k_vt<<<dim3(Ss / 32, HD / 32, Bb * NKV), dim3(256), 0, stream>>>(kvf, vt16, 1024, 512);
  // 6. flash attention
  k_flash<<<dim3(16, NH, Bb), dim3(256), 0, stream>>>(qb16, kb16, vt16, o16);
  // 7. output projection -> fp32 out
  k_gemm<<<dim3(16, 32), dim3(256), 0, stream>>>(o16, woT, out, MROWS, 2048, 2048);
}

// Round 3
// 357.872 us; speedup vs baseline: 1.3019x; 1.3019x over previous
//
#include <hip/hip_runtime.h>
#include <cstdint>
#include <cstddef>

typedef unsigned short u16;
typedef __attribute__((ext_vector_type(8))) short short8;
typedef __attribute__((ext_vector_type(4))) float floatx4;

#define DEVI __device__ __forceinline__

constexpr int Bb  = 2;
constexpr int Ss  = 2048;
constexpr int Hh  = 2048;
constexpr int NH  = 16;
constexpr int NKV = 4;
constexpr int HD  = 128;
constexpr int MROWS = Bb * Ss;  // 4096

DEVI u16 f2bf(float f) {
  union { float f; unsigned u; } v; v.f = f;
  unsigned r = v.u + 0x7fffu + ((v.u >> 16) & 1u);
  return (u16)(r >> 16);
}
DEVI float bf2f(u16 v) {
  union { unsigned u; float f; } x; x.u = ((unsigned)v) << 16; return x.f;
}

// async global->LDS, 16B per lane. LDS dest must be wave-uniform base + lane*16.
DEVI void llds16(const u16* g, u16* l) {
  __builtin_amdgcn_global_load_lds(
      (const __attribute__((address_space(1))) void*)g,
      (__attribute__((address_space(3))) void*)l, 16, 0, 0);
}

// ---------- fp32 -> bf16 convert (vectorized) ----------
__global__ void k_f2b(const float4* __restrict__ in, ushort4* __restrict__ out, int n4) {
  int i = blockIdx.x * blockDim.x + threadIdx.x;
  if (i < n4) {
    float4 v = in[i];
    ushort4 o;
    o.x = f2bf(v.x); o.y = f2bf(v.y); o.z = f2bf(v.z); o.w = f2bf(v.w);
    out[i] = o;
  }
}

// ---------- transpose + convert: in (K,N) fp32 row-major -> out (N,K) bf16 ----------
__global__ void k_tw(const float* __restrict__ in, u16* __restrict__ out, int K, int N) {
  __shared__ float tile[32][33];
  int n0 = blockIdx.x * 32, k0 = blockIdx.y * 32;
  int tx = threadIdx.x & 31, ty = threadIdx.x >> 5;  // 256 threads
  for (int i = ty; i < 32; i += 8)
    tile[i][tx] = in[(size_t)(k0 + i) * N + n0 + tx];
  __syncthreads();
  for (int i = ty; i < 32; i += 8)
    out[(size_t)(n0 + i) * K + k0 + tx] = f2bf(tile[tx][i]);
}

// ---------- m97-style GEMM, XOR-swizzled LDS: C(M,N) = A(M,K) bf16 @ Bt(N,K)^T bf16 ----------
// 128x128 tile, BK=32, 256 threads / 4 waves, 16x16x32 bf16 MFMA.
// LDS chunk swizzle: row of 4x16B chunks; chunk c stored at c^(row&3) -> b128 reads 4-way not 8-way.
template <bool BF16_OUT>
__global__ __launch_bounds__(256) void k_gemm(const u16* __restrict__ A, const u16* __restrict__ Bt,
                                              void* __restrict__ Cv, int M, int N, int K) {
  __shared__ u16 As[128 * 32];
  __shared__ u16 Bs[128 * 32];
  const int t = threadIdx.x;
  const int lane = t & 63, w = t >> 6;
  const int q4 = lane >> 4, l16 = lane & 15;
  const int sw3 = l16 & 3;
  const int m0 = blockIdx.y * 128, n0 = blockIdx.x * 128;
  const int wm = (w >> 1) * 64, wn = (w & 1) * 64;

  floatx4 acc[4][4];
#pragma unroll
  for (int i = 0; i < 4; ++i)
#pragma unroll
    for (int j = 0; j < 4; ++j) acc[i][j] = floatx4{0.f, 0.f, 0.f, 0.f};

  const u16* Ab = A + (size_t)m0 * K;
  const u16* Bp = Bt + (size_t)n0 * K;

  for (int k0 = 0; k0 < K; k0 += 32) {
#pragma unroll
    for (int it = 0; it < 2; ++it) {
      int c = it * 256 + t;            // 512 chunks of 16B per 128x32 tile
      int row = c >> 2, pc = c & 3;
      int gc = pc ^ (row & 3);         // fetch swizzled source chunk
      llds16(Ab + (size_t)row * K + k0 + gc * 8, &As[c * 8]);
      llds16(Bp + (size_t)row * K + k0 + gc * 8, &Bs[c * 8]);
    }
    __syncthreads();
    short8 af[4], bfr[4];
#pragma unroll
    for (int tm = 0; tm < 4; ++tm)
      af[tm] = *(const short8*)&As[(wm + tm * 16 + l16) * 32 + (q4 ^ sw3) * 8];
#pragma unroll
    for (int tn = 0; tn < 4; ++tn)
      bfr[tn] = *(const short8*)&Bs[(wn + tn * 16 + l16) * 32 + (q4 ^ sw3) * 8];
#pragma unroll
    for (int tm = 0; tm < 4; ++tm)
#pragma unroll
      for (int tn = 0; tn < 4; ++tn)
        acc[tm][tn] = __builtin_amdgcn_mfma_f32_16x16x32_bf16(af[tm], bfr[tn], acc[tm][tn], 0, 0, 0);
    __syncthreads();
  }
  // C/D layout: col = lane&15, row = quad*4 + reg (m89-verified)
#pragma unroll
  for (int tm = 0; tm < 4; ++tm) {
    int rb = m0 + wm + tm * 16 + q4 * 4;
#pragma unroll
    for (int tn = 0; tn < 4; ++tn) {
      int col = n0 + wn + tn * 16 + l16;
#pragma unroll
      for (int r = 0; r < 4; ++r) {
        if constexpr (BF16_OUT)
          ((u16*)Cv)[(size_t)(rb + r) * N + col] = f2bf(acc[tm][tn][r]);
        else
          ((float*)Cv)[(size_t)(rb + r) * N + col] = acc[tm][tn][r];
      }
    }
  }
}

// ---------- RoPE: in bf16 (B,S,instride cols; head at coloff+h*HD) -> out bf16 (B,S,nheads,HD) ----------
__global__ void k_rope(const u16* __restrict__ in, u16* __restrict__ out,
                       int nheads, int instride, int coloff, float scale) {
  int idx = blockIdx.x * blockDim.x + threadIdx.x;
  int j = idx & 63;
  int tmp = idx >> 6;
  int h = tmp % nheads; tmp /= nheads;   // tmp = b*S + s
  int s = tmp % Ss;
  const u16* ip = in + (size_t)tmp * instride + coloff + h * HD;
  u16* op = out + ((size_t)tmp * nheads + h) * HD;
  float inv = exp2f(-(float)(2 * j) * (13.287712379549449f / (float)HD));
  float ang = (float)s * inv;
  float c = cosf(ang), sn = sinf(ang);
  float x1 = bf2f(ip[j]), x2 = bf2f(ip[j + 64]);
  op[j]      = f2bf((x1 * c - x2 * sn) * scale);
  op[j + 64] = f2bf((x2 * c + x1 * sn) * scale);
}

// ---------- V transpose: bf16 (B,S,cols of instride; coloff+g*HD+d) -> bf16 Vt (B,NKV,HD,S) ----------
__global__ void k_vt(const u16* __restrict__ V, u16* __restrict__ Vt, int instride, int coloff) {
  __shared__ u16 tile[32][33];
  int bg = blockIdx.z;                 // b*NKV + g
  int s0 = blockIdx.x * 32;
  int d0 = blockIdx.y * 32;
  int tx = threadIdx.x & 31, ty = threadIdx.x >> 5;
  int b = bg / NKV, g = bg % NKV;
  const u16* vin = V + (size_t)(b * Ss) * instride + coloff + g * HD;
  for (int i = ty; i < 32; i += 8)
    tile[i][tx] = vin[(size_t)(s0 + i) * instride + d0 + tx];
  __syncthreads();
  u16* vout = Vt + (size_t)bg * HD * Ss;
  for (int i = ty; i < 32; i += 8)
    vout[(size_t)(d0 + i) * Ss + s0 + tx] = tile[tx][i];
}

// ---------- flash attention: Q(B,S,NH,HD) bf16 (pre-scaled), K(B,S,NKV,HD) bf16, Vt(B,NKV,HD,S) bf16 ----------
// 64-row Q tile x 64-key tile, 4 waves (16 q-rows each). Block handles qb = x and 31-x (balanced triangle).
// K/V LDS double-buffered; 16B-chunk XOR swizzle (chunk c of row r stored at c^(r&7)) -> conflict-free b128.
__global__ __launch_bounds__(256) void k_flash(const u16* __restrict__ Q, const u16* __restrict__ Kk,
                                               const u16* __restrict__ Vt, u16* __restrict__ O) {
  __shared__ u16 Kts[2][64 * 128];   // [sk][d], swizzled
  __shared__ u16 Vts[2][128 * 64];   // [d][sk], swizzled
  __shared__ u16 Ps[64 * 72];        // [q][sk], rows padded to 72 u16 (9 chunks)
  const int t = threadIdx.x, lane = t & 63, w = t >> 6;
  const int q4 = lane >> 4, l16 = lane & 15;
  const int sw8 = l16 & 7;
  const int h = blockIdx.y, b = blockIdx.z, g = h >> 2;  // NREP=4
  const u16* Qh = Q + ((size_t)b * Ss * NH + h) * HD;
  const u16* Kh = Kk + ((size_t)b * Ss * NKV + g) * HD;
  const u16* Vh = Vt + (size_t)(b * NKV + g) * HD * Ss;
  u16* Oh = O + ((size_t)b * Ss * NH + h) * HD;

  auto stage = [&](int k0, int buf) {
#pragma unroll
    for (int it = 0; it < 4; ++it) {
      int c = it * 256 + t;                       // 1024 chunks each
      int krow = c >> 4, kpc = c & 15;
      llds16(Kh + (size_t)(k0 + krow) * (NKV * HD) + (kpc ^ (krow & 7)) * 8, &Kts[buf][c * 8]);
      int vrow = c >> 3, vpc = c & 7;
      llds16(Vh + (size_t)vrow * Ss + k0 + (vpc ^ (vrow & 7)) * 8, &Vts[buf][c * 8]);
    }
  };

  int cur = 0;
  for (int hf = 0; hf < 2; ++hf) {
    const int qb = hf ? (31 - (int)blockIdx.x) : (int)blockIdx.x;
    const int q0 = qb * 64;
    // Q fragments (loop-invariant): A-layout A[m=lane&15][k=quad*8+j]
    const int qrow = q0 + w * 16 + l16;
    short8 qf[4];
#pragma unroll
    for (int kt = 0; kt < 4; ++kt)
      qf[kt] = *(const short8*)&Qh[(size_t)qrow * (NH * HD) + kt * 32 + q4 * 8];

    floatx4 oacc[8];
#pragma unroll
    for (int i = 0; i < 8; ++i) oacc[i] = floatx4{0.f, 0.f, 0.f, 0.f};
    float m_i[4] = {-1e30f, -1e30f, -1e30f, -1e30f};
    float l_p[4] = {0.f, 0.f, 0.f, 0.f};   // per-lane partial denominators

    stage(0, cur);   // prologue; buffer free since last sync of previous half

    for (int kb = 0; kb <= qb; ++kb) {
      __syncthreads();                       // drains staging of buf[cur] (and prev prefetch)
      if (kb < qb) stage((kb + 1) * 64, cur ^ 1);   // in flight across compute
      const u16* Kb = Kts[cur];
      const u16* Vb = Vts[cur];

      // S = Q K^T : 16 rows x 64 keys per wave
      floatx4 sc[4];
#pragma unroll
      for (int tn = 0; tn < 4; ++tn) sc[tn] = floatx4{0.f, 0.f, 0.f, 0.f};
#pragma unroll
      for (int kt = 0; kt < 4; ++kt)
#pragma unroll
        for (int tn = 0; tn < 4; ++tn) {
          short8 bfr = *(const short8*)&Kb[(tn * 16 + l16) * 128 + ((kt * 4 + q4) ^ sw8) * 8];
          sc[tn] = __builtin_amdgcn_mfma_f32_16x16x32_bf16(qf[kt], bfr, sc[tn], 0, 0, 0);
        }

      if (kb == qb) {  // diagonal block: mask col > row (row includes wave's 16-row band)
#pragma unroll
        for (int tn = 0; tn < 4; ++tn) {
          int col = tn * 16 + l16;
#pragma unroll
          for (int r = 0; r < 4; ++r)
            if (col > w * 16 + q4 * 4 + r) sc[tn][r] = -1e30f;
        }
      }

      // online softmax; row r lives in quad q4, cols spread over 16 lanes
#pragma unroll
      for (int r = 0; r < 4; ++r) {
        float v = fmaxf(fmaxf(sc[0][r], sc[1][r]), fmaxf(sc[2][r], sc[3][r]));
#pragma unroll
        for (int off = 1; off < 16; off <<= 1) v = fmaxf(v, __shfl_xor(v, off));
        float mnew = fmaxf(m_i[r], v);
        float alpha = __expf(m_i[r] - mnew);
        m_i[r] = mnew;
        float rs = 0.f;
#pragma unroll
        for (int tn = 0; tn < 4; ++tn) {
          float p = __expf(sc[tn][r] - mnew);
          sc[tn][r] = p;
          rs += p;
        }
        l_p[r] = l_p[r] * alpha + rs;        // per-lane partial; reduced once at end
#pragma unroll
        for (int td = 0; td < 8; ++td) oacc[td][r] *= alpha;
      }

      // P: C-layout -> LDS row-major (padded) -> A-layout reads (wave-private rows, no barrier)
#pragma unroll
      for (int tn = 0; tn < 4; ++tn)
#pragma unroll
        for (int r = 0; r < 4; ++r)
          Ps[(w * 16 + q4 * 4 + r) * 72 + tn * 16 + l16] = f2bf(sc[tn][r]);

      // O += P V
#pragma unroll
      for (int kt2 = 0; kt2 < 2; ++kt2) {
        short8 pa = *(const short8*)&Ps[(w * 16 + l16) * 72 + kt2 * 32 + q4 * 8];
#pragma unroll
        for (int td = 0; td < 8; ++td) {
          short8 vb = *(const short8*)&Vb[(td * 16 + l16) * 64 + ((kt2 * 4 + q4) ^ sw8) * 8];
          oacc[td] = __builtin_amdgcn_mfma_f32_16x16x32_bf16(pa, vb, oacc[td], 0, 0, 0);
        }
      }
      cur ^= 1;
    }

    // final denominator reduce (4 shfl per row, once)
    float linv[4];
#pragma unroll
    for (int r = 0; r < 4; ++r) {
      float l = l_p[r];
#pragma unroll
      for (int off = 1; off < 16; off <<= 1) l += __shfl_xor(l, off);
      linv[r] = 1.f / l;
    }
    // epilogue: O row = q0 + w*16 + quad*4 + r, col = td*16 + lane&15
#pragma unroll
    for (int td = 0; td < 8; ++td)
#pragma unroll
      for (int r = 0; r < 4; ++r)
        Oh[(size_t)(q0 + w * 16 + q4 * 4 + r) * (NH * HD) + td * 16 + l16] = f2bf(oacc[td][r] * linv[r]);
  }
}

extern "C" void kernel_launch(void* const* d_in, const int* in_sizes, int n_in,
                              void* d_out, int out_size, void* d_ws, size_t ws_size,
                              hipStream_t stream) {
  (void)in_sizes; (void)n_in; (void)out_size; (void)ws_size;
  const float* x  = (const float*)d_in[0];
  const float* wq = (const float*)d_in[1];
  const float* wk = (const float*)d_in[2];
  const float* wv = (const float*)d_in[3];
  const float* wo = (const float*)d_in[4];
  float* out = (float*)d_out;

  char* ws = (char*)d_ws;
  size_t off = 0;
  auto alloc = [&](size_t bytes) {
    char* p = ws + off;
    off += (bytes + 255) & ~(size_t)255;
    return (void*)p;
  };
  u16* xb     = (u16*)alloc((size_t)MROWS * Hh * 2);        // reused as O (bf16) later
  u16* wqkvT  = (u16*)alloc((size_t)3072 * 2048 * 2);       // rows: [wqT 0..2047 | wkT 2048..2559 | wvT 2560..3071]
  u16* woT    = (u16*)alloc((size_t)2048 * 2048 * 2);
  u16* qkv16  = (u16*)alloc((size_t)MROWS * 3072 * 2);      // fused projection output, bf16
  u16* qb16   = (u16*)alloc((size_t)MROWS * 2048 * 2);
  u16* kb16   = (u16*)alloc((size_t)MROWS * 512 * 2);
  u16* vt16   = (u16*)alloc((size_t)MROWS * 512 * 2);
  u16* o16    = xb;  // xb dead after QKV projection

  // 1. x -> bf16
  k_f2b<<<dim3((MROWS * Hh / 4 + 255) / 256), dim3(256), 0, stream>>>(
      (const float4*)x, (ushort4*)xb, MROWS * Hh / 4);
  // 2. weights -> transposed bf16 (fused QKV weight)
  k_tw<<<dim3(64, 64), dim3(256), 0, stream>>>(wq, wqkvT, 2048, 2048);
  k_tw<<<dim3(16, 64), dim3(256), 0, stream>>>(wk, wqkvT + (size_t)2048 * 2048, 2048, 512);
  k_tw<<<dim3(16, 64), dim3(256), 0, stream>>>(wv, wqkvT + (size_t)2560 * 2048, 2048, 512);
  k_tw<<<dim3(64, 64), dim3(256), 0, stream>>>(wo, woT, 2048, 2048);
  // 3. fused QKV projection: (4096,2048) @ (2048,3072) -> bf16 (4096,3072); 768 blocks = 3/CU
  k_gemm<true><<<dim3(24, 32), dim3(256), 0, stream>>>(xb, wqkvT, qkv16, MROWS, 3072, 2048);
  // 4. RoPE (fold 1/sqrt(HD) into Q)
  k_rope<<<dim3(Bb * Ss * NH * 64 / 256), dim3(256), 0, stream>>>(
      qkv16, qb16, NH, 3072, 0, 0.08838834764831845f);
  k_rope<<<dim3(Bb * Ss * NKV * 64 / 256), dim3(256), 0, stream>>>(
      qkv16, kb16, NKV, 3072, 2048, 1.0f);
  // 5. V -> (B,NKV,HD,S) bf16
  k_vt<<<dim3(Ss / 32, HD / 32, Bb * NKV), dim3(256), 0, stream>>>(qkv16, vt16, 3072, 2560);
  // 6. flash attention
  k_flash<<<dim3(16, NH, Bb), dim3(256), 0, stream>>>(qb16, kb16, vt16, o16);
  // 7. output projection -> fp32 out
  k_gemm<false><<<dim3(16, 32), dim3(256), 0, stream>>>(o16, woT, out, MROWS, 2048, 2048);
}

// Round 4
// 341.707 us; speedup vs baseline: 1.3635x; 1.0473x over previous
//
#include <hip/hip_runtime.h>
#include <cstdint>
#include <cstddef>

typedef unsigned short u16;
typedef __attribute__((ext_vector_type(8))) short short8;
typedef __attribute__((ext_vector_type(4))) float floatx4;

#define DEVI __device__ __forceinline__

constexpr int Bb  = 2;
constexpr int Ss  = 2048;
constexpr int Hh  = 2048;
constexpr int NH  = 16;
constexpr int NKV = 4;
constexpr int HD  = 128;
constexpr int MROWS = Bb * Ss;  // 4096

DEVI u16 f2bf(float f) {
  union { float f; unsigned u; } v; v.f = f;
  unsigned r = v.u + 0x7fffu + ((v.u >> 16) & 1u);
  return (u16)(r >> 16);
}
DEVI float bf2f(u16 v) {
  union { unsigned u; float f; } x; x.u = ((unsigned)v) << 16; return x.f;
}
// pack two fp32 into (bf16(b)<<16)|bf16(a), round-half-up via +0x8000 then byte-perm
DEVI unsigned pkbf(float a, float b) {
  union { float f; unsigned u; } ua, ub; ua.f = a; ub.f = b;
  return __builtin_amdgcn_perm(ub.u + 0x8000u, ua.u + 0x8000u, 0x07060302u);
}

// async global->LDS, 16B per lane. LDS dest must be wave-uniform base + lane*16.
DEVI void llds16(const u16* g, u16* l) {
  __builtin_amdgcn_global_load_lds(
      (const __attribute__((address_space(1))) void*)g,
      (__attribute__((address_space(3))) void*)l, 16, 0, 0);
}

// ---------- fp32 -> bf16 convert (vectorized) ----------
__global__ void k_f2b(const float4* __restrict__ in, ushort4* __restrict__ out, int n4) {
  int i = blockIdx.x * blockDim.x + threadIdx.x;
  if (i < n4) {
    float4 v = in[i];
    ushort4 o;
    o.x = f2bf(v.x); o.y = f2bf(v.y); o.z = f2bf(v.z); o.w = f2bf(v.w);
    out[i] = o;
  }
}

// ---------- transpose + convert: in (K,N) fp32 row-major -> out (N,K) bf16 ----------
__global__ void k_tw(const float* __restrict__ in, u16* __restrict__ out, int K, int N) {
  __shared__ float tile[32][33];
  int n0 = blockIdx.x * 32, k0 = blockIdx.y * 32;
  int tx = threadIdx.x & 31, ty = threadIdx.x >> 5;  // 256 threads
  for (int i = ty; i < 32; i += 8)
    tile[i][tx] = in[(size_t)(k0 + i) * N + n0 + tx];
  __syncthreads();
  for (int i = ty; i < 32; i += 8)
    out[(size_t)(n0 + i) * K + k0 + tx] = f2bf(tile[tx][i]);
}

// ---------- m97-style GEMM, XOR-swizzled LDS: C(M,N) = A(M,K) bf16 @ Bt(N,K)^T bf16 ----------
template <bool BF16_OUT>
__global__ __launch_bounds__(256) void k_gemm(const u16* __restrict__ A, const u16* __restrict__ Bt,
                                              void* __restrict__ Cv, int M, int N, int K) {
  __shared__ u16 As[128 * 32];
  __shared__ u16 Bs[128 * 32];
  const int t = threadIdx.x;
  const int lane = t & 63, w = t >> 6;
  const int q4 = lane >> 4, l16 = lane & 15;
  const int sw3 = l16 & 3;
  const int m0 = blockIdx.y * 128, n0 = blockIdx.x * 128;
  const int wm = (w >> 1) * 64, wn = (w & 1) * 64;

  floatx4 acc[4][4];
#pragma unroll
  for (int i = 0; i < 4; ++i)
#pragma unroll
    for (int j = 0; j < 4; ++j) acc[i][j] = floatx4{0.f, 0.f, 0.f, 0.f};

  const u16* Ab = A + (size_t)m0 * K;
  const u16* Bp = Bt + (size_t)n0 * K;

  for (int k0 = 0; k0 < K; k0 += 32) {
#pragma unroll
    for (int it = 0; it < 2; ++it) {
      int c = it * 256 + t;            // 512 chunks of 16B per 128x32 tile
      int row = c >> 2, pc = c & 3;
      int gc = pc ^ (row & 3);         // fetch swizzled source chunk
      llds16(Ab + (size_t)row * K + k0 + gc * 8, &As[c * 8]);
      llds16(Bp + (size_t)row * K + k0 + gc * 8, &Bs[c * 8]);
    }
    __syncthreads();
    short8 af[4], bfr[4];
#pragma unroll
    for (int tm = 0; tm < 4; ++tm)
      af[tm] = *(const short8*)&As[(wm + tm * 16 + l16) * 32 + (q4 ^ sw3) * 8];
#pragma unroll
    for (int tn = 0; tn < 4; ++tn)
      bfr[tn] = *(const short8*)&Bs[(wn + tn * 16 + l16) * 32 + (q4 ^ sw3) * 8];
#pragma unroll
    for (int tm = 0; tm < 4; ++tm)
#pragma unroll
      for (int tn = 0; tn < 4; ++tn)
        acc[tm][tn] = __builtin_amdgcn_mfma_f32_16x16x32_bf16(af[tm], bfr[tn], acc[tm][tn], 0, 0, 0);
    __syncthreads();
  }
  // C/D layout: col = lane&15, row = quad*4 + reg (m89-verified)
#pragma unroll
  for (int tm = 0; tm < 4; ++tm) {
    int rb = m0 + wm + tm * 16 + q4 * 4;
#pragma unroll
    for (int tn = 0; tn < 4; ++tn) {
      int col = n0 + wn + tn * 16 + l16;
#pragma unroll
      for (int r = 0; r < 4; ++r) {
        if constexpr (BF16_OUT)
          ((u16*)Cv)[(size_t)(rb + r) * N + col] = f2bf(acc[tm][tn][r]);
        else
          ((float*)Cv)[(size_t)(rb + r) * N + col] = acc[tm][tn][r];
      }
    }
  }
}

// ---------- RoPE: in bf16 (B,S,instride cols; head at coloff+h*HD) -> out bf16 (B,S,nheads,HD) ----------
__global__ void k_rope(const u16* __restrict__ in, u16* __restrict__ out,
                       int nheads, int instride, int coloff, float scale) {
  int idx = blockIdx.x * blockDim.x + threadIdx.x;
  int j = idx & 63;
  int tmp = idx >> 6;
  int h = tmp % nheads; tmp /= nheads;   // tmp = b*S + s
  int s = tmp % Ss;
  const u16* ip = in + (size_t)tmp * instride + coloff + h * HD;
  u16* op = out + ((size_t)tmp * nheads + h) * HD;
  float inv = exp2f(-(float)(2 * j) * (13.287712379549449f / (float)HD));
  float ang = (float)s * inv;
  float c = cosf(ang), sn = sinf(ang);
  float x1 = bf2f(ip[j]), x2 = bf2f(ip[j + 64]);
  op[j]      = f2bf((x1 * c - x2 * sn) * scale);
  op[j + 64] = f2bf((x2 * c + x1 * sn) * scale);
}

// ---------- V transpose: bf16 (B,S,cols of instride; coloff+g*HD+d) -> bf16 Vt (B,NKV,HD,S) ----------
__global__ void k_vt(const u16* __restrict__ V, u16* __restrict__ Vt, int instride, int coloff) {
  __shared__ u16 tile[32][33];
  int bg = blockIdx.z;                 // b*NKV + g
  int s0 = blockIdx.x * 32;
  int d0 = blockIdx.y * 32;
  int tx = threadIdx.x & 31, ty = threadIdx.x >> 5;
  int b = bg / NKV, g = bg % NKV;
  const u16* vin = V + (size_t)(b * Ss) * instride + coloff + g * HD;
  for (int i = ty; i < 32; i += 8)
    tile[i][tx] = vin[(size_t)(s0 + i) * instride + d0 + tx];
  __syncthreads();
  u16* vout = Vt + (size_t)bg * HD * Ss;
  for (int i = ty; i < 32; i += 8)
    vout[(size_t)(d0 + i) * Ss + s0 + tx] = tile[tx][i];
}

// ---------- flash attention, S^T formulation ----------
// Q pre-scaled by log2(e)/sqrt(HD); scores in base-2 domain. Each lane owns ONE q-column.
// S^T = K Q^T via mfma(kfrag, qfrag): C tile [key][q]; O^T = V^T P^T via mfma(vfrag, pfrag).
__global__ __launch_bounds__(256) void k_flash(const u16* __restrict__ Q, const u16* __restrict__ Kk,
                                               const u16* __restrict__ Vt, u16* __restrict__ O) {
  __shared__ u16 Kts[2][64 * 128];   // [sk][d], 16B-chunk XOR swizzled
  __shared__ u16 Vts[2][128 * 64];   // [d][sk], swizzled
  __shared__ u16 Ps[64 * 72];        // P^T [q][sk], rows padded to 72
  const int t = threadIdx.x, lane = t & 63, w = t >> 6;
  const int q4 = lane >> 4, l16 = lane & 15;
  const int sw8 = l16 & 7;
  const int h = blockIdx.y, b = blockIdx.z, g = h >> 2;  // NREP=4
  const u16* Qh = Q + ((size_t)b * Ss * NH + h) * HD;
  const u16* Kh = Kk + ((size_t)b * Ss * NKV + g) * HD;
  const u16* Vh = Vt + (size_t)(b * NKV + g) * HD * Ss;
  u16* Oh = O + ((size_t)b * Ss * NH + h) * HD;
  const int wl = w * 16 + l16;       // this lane's q within the 64-row tile

  auto stage = [&](int k0, int buf) {
#pragma unroll
    for (int it = 0; it < 4; ++it) {
      int c = it * 256 + t;                       // 1024 chunks each
      int krow = c >> 4, kpc = c & 15;
      llds16(Kh + (size_t)(k0 + krow) * (NKV * HD) + (kpc ^ (krow & 7)) * 8, &Kts[buf][c * 8]);
      int vrow = c >> 3, vpc = c & 7;
      llds16(Vh + (size_t)vrow * Ss + k0 + (vpc ^ (vrow & 7)) * 8, &Vts[buf][c * 8]);
    }
  };

  int cur = 0;
  for (int hf = 0; hf < 2; ++hf) {
    const int qb = hf ? (31 - (int)blockIdx.x) : (int)blockIdx.x;
    const int q0 = qb * 64;
    // Q fragment (loop-invariant): B-operand B[n=q=l16][k=d=q4*8+j]
    const int qrow = q0 + wl;
    short8 qf[4];
#pragma unroll
    for (int kt = 0; kt < 4; ++kt)
      qf[kt] = *(const short8*)&Qh[(size_t)qrow * (NH * HD) + kt * 32 + q4 * 8];

    floatx4 oacc[8];                  // O^T: d = td*16 + q4*4 + r, q = l16 (this lane's)
#pragma unroll
    for (int i = 0; i < 8; ++i) oacc[i] = floatx4{0.f, 0.f, 0.f, 0.f};
    float m_i = -1e30f, l_p = 0.f;    // single q-row state per lane

    stage(0, cur);

    for (int kb = 0; kb <= qb; ++kb) {
      __syncthreads();
      if (kb < qb) stage((kb + 1) * 64, cur ^ 1);
      const u16* Kb = Kts[cur];
      const u16* Vb = Vts[cur];

      // S^T = K Q^T : keys (rows) x 16 q (cols); per lane: keys tn*16+q4*4+r, q = wl
      floatx4 sc[4];
#pragma unroll
      for (int tn = 0; tn < 4; ++tn) sc[tn] = floatx4{0.f, 0.f, 0.f, 0.f};
#pragma unroll
      for (int kt = 0; kt < 4; ++kt)
#pragma unroll
        for (int tn = 0; tn < 4; ++tn) {
          short8 kfr = *(const short8*)&Kb[(tn * 16 + l16) * 128 + ((kt * 4 + q4) ^ sw8) * 8];
          sc[tn] = __builtin_amdgcn_mfma_f32_16x16x32_bf16(kfr, qf[kt], sc[tn], 0, 0, 0);
        }

      if (kb == qb) {  // diagonal: mask key > q (both tile-local)
#pragma unroll
        for (int tn = 0; tn < 4; ++tn) {
          int keyb = tn * 16 + q4 * 4;
#pragma unroll
          for (int r = 0; r < 4; ++r)
            if (keyb + r > wl) sc[tn][r] = -1e30f;
        }
      }

      // online softmax (base-2): lane reduces its 16 keys, then across quads (^16, ^32)
      float vmax = sc[0][0];
#pragma unroll
      for (int tn = 0; tn < 4; ++tn)
#pragma unroll
        for (int r = 0; r < 4; ++r) vmax = fmaxf(vmax, sc[tn][r]);
      vmax = fmaxf(vmax, __shfl_xor(vmax, 16));
      vmax = fmaxf(vmax, __shfl_xor(vmax, 32));
      float mnew = fmaxf(m_i, vmax);
      float alpha = __builtin_amdgcn_exp2f(m_i - mnew);
      m_i = mnew;
      float rs = 0.f;
#pragma unroll
      for (int tn = 0; tn < 4; ++tn)
#pragma unroll
        for (int r = 0; r < 4; ++r) {
          float p = __builtin_amdgcn_exp2f(sc[tn][r] - mnew);
          sc[tn][r] = p;
          rs += p;
        }
      l_p = l_p * alpha + rs;          // per-lane partial (quad-reduced at end)
#pragma unroll
      for (int td = 0; td < 8; ++td) oacc[td] *= alpha;

      // P^T store: lane's 4 consecutive keys per tn -> packed b64, row = wl (wave-private)
#pragma unroll
      for (int tn = 0; tn < 4; ++tn) {
        uint2 pk;
        pk.x = pkbf(sc[tn][0], sc[tn][1]);
        pk.y = pkbf(sc[tn][2], sc[tn][3]);
        *(uint2*)&Ps[(size_t)wl * 72 + tn * 16 + q4 * 4] = pk;
      }

      // O^T += V^T P^T
#pragma unroll
      for (int kt2 = 0; kt2 < 2; ++kt2) {
        short8 pfr = *(const short8*)&Ps[(size_t)wl * 72 + kt2 * 32 + q4 * 8];
#pragma unroll
        for (int td = 0; td < 8; ++td) {
          short8 vfr = *(const short8*)&Vb[(td * 16 + l16) * 64 + ((kt2 * 4 + q4) ^ sw8) * 8];
          oacc[td] = __builtin_amdgcn_mfma_f32_16x16x32_bf16(vfr, pfr, oacc[td], 0, 0, 0);
        }
      }
      cur ^= 1;
    }

    // final denominator: reduce partials across quads
    float l = l_p;
    l += __shfl_xor(l, 16);
    l += __shfl_xor(l, 32);
    float linv = 1.f / l;
    // epilogue: lane owns q-row qrow; d = td*16 + q4*4 + r -> 4 consecutive bf16 = 8B store
#pragma unroll
    for (int td = 0; td < 8; ++td) {
      uint2 pk;
      pk.x = pkbf(oacc[td][0] * linv, oacc[td][1] * linv);
      pk.y = pkbf(oacc[td][2] * linv, oacc[td][3] * linv);
      *(uint2*)&Oh[(size_t)qrow * (NH * HD) + td * 16 + q4 * 4] = pk;
    }
  }
}

extern "C" void kernel_launch(void* const* d_in, const int* in_sizes, int n_in,
                              void* d_out, int out_size, void* d_ws, size_t ws_size,
                              hipStream_t stream) {
  (void)in_sizes; (void)n_in; (void)out_size; (void)ws_size;
  const float* x  = (const float*)d_in[0];
  const float* wq = (const float*)d_in[1];
  const float* wk = (const float*)d_in[2];
  const float* wv = (const float*)d_in[3];
  const float* wo = (const float*)d_in[4];
  float* out = (float*)d_out;

  char* ws = (char*)d_ws;
  size_t off = 0;
  auto alloc = [&](size_t bytes) {
    char* p = ws + off;
    off += (bytes + 255) & ~(size_t)255;
    return (void*)p;
  };
  u16* xb     = (u16*)alloc((size_t)MROWS * Hh * 2);        // reused as O (bf16) later
  u16* wqkvT  = (u16*)alloc((size_t)3072 * 2048 * 2);       // [wqT | wkT | wvT]
  u16* woT    = (u16*)alloc((size_t)2048 * 2048 * 2);
  u16* qkv16  = (u16*)alloc((size_t)MROWS * 3072 * 2);      // fused projection output, bf16
  u16* qb16   = (u16*)alloc((size_t)MROWS * 2048 * 2);
  u16* kb16   = (u16*)alloc((size_t)MROWS * 512 * 2);
  u16* vt16   = (u16*)alloc((size_t)MROWS * 512 * 2);
  u16* o16    = xb;  // xb dead after QKV projection

  // 1. x -> bf16
  k_f2b<<<dim3((MROWS * Hh / 4 + 255) / 256), dim3(256), 0, stream>>>(
      (const float4*)x, (ushort4*)xb, MROWS * Hh / 4);
  // 2. weights -> transposed bf16 (fused QKV weight)
  k_tw<<<dim3(64, 64), dim3(256), 0, stream>>>(wq, wqkvT, 2048, 2048);
  k_tw<<<dim3(16, 64), dim3(256), 0, stream>>>(wk, wqkvT + (size_t)2048 * 2048, 2048, 512);
  k_tw<<<dim3(16, 64), dim3(256), 0, stream>>>(wv, wqkvT + (size_t)2560 * 2048, 2048, 512);
  k_tw<<<dim3(64, 64), dim3(256), 0, stream>>>(wo, woT, 2048, 2048);
  // 3. fused QKV projection -> bf16 (4096,3072)
  k_gemm<true><<<dim3(24, 32), dim3(256), 0, stream>>>(xb, wqkvT, qkv16, MROWS, 3072, 2048);
  // 4. RoPE; Q scale folds 1/sqrt(HD) * log2(e) (flash works in base-2 domain)
  k_rope<<<dim3(Bb * Ss * NH * 64 / 256), dim3(256), 0, stream>>>(
      qkv16, qb16, NH, 3072, 0, 0.08838834764831845f * 1.4426950408889634f);
  k_rope<<<dim3(Bb * Ss * NKV * 64 / 256), dim3(256), 0, stream>>>(
      qkv16, kb16, NKV, 3072, 2048, 1.0f);
  // 5. V -> (B,NKV,HD,S) bf16
  k_vt<<<dim3(Ss / 32, HD / 32, Bb * NKV), dim3(256), 0, stream>>>(qkv16, vt16, 3072, 2560);
  // 6. flash attention
  k_flash<<<dim3(16, NH, Bb), dim3(256), 0, stream>>>(qb16, kb16, vt16, o16);
  // 7. output projection -> fp32 out
  k_gemm<false><<<dim3(16, 32), dim3(256), 0, stream>>>(o16, woT, out, MROWS, 2048, 2048);
}